// Round 8
// baseline (207.445 us; speedup 1.0000x reference)
//
#include <hip/hip_runtime.h>
#include <hip/hip_bf16.h>

// B=512, I=1152, K=8, L=16, O=7; IK=9216, LO=112.
// Round-7: fused kernel, fenceless barriers (R6), PLUS:
//  - wps eliminated: sq scales B in-register from eb (R0 numerics, proven
//    invisible VALU cost). B-operand = STATIC wpT -> L2-hot all 3 iters.
//    R6's FETCH breakdown showed the ping-ponged wps cost ~19 MB/iter of
//    L3 refetch (8 XCDs x 2.36 MB) = the dominant term of its 148 us.
//    Cross-phase payload now: eb 72KB + vT 114KB + Z per iter (~200 KB).
//  - 1024 thr/block (16 waves/CU, R0's sq geometry) for 2x latency hiding.
// Cross-phase buffers ping-ponged (eb0/eb1, vT0/vT1, Z per-iter lines) ->
// consumers only read VIRGIN addresses (fresh from L3); producers write
// them with agent-scope stores (bypass L2 -> L3). R6 hardware-proved
// WT-store -> fenceless bar -> normal-load is correct cross-XCD.
// One fenced barrier (post-prep) publishes xbf/xT/wpT + flushes fill poison.
// Phases: prep | FENCE-bar | 3x { sq | bar | g | bar }:
//   sq(it): s = xbf . (wpT scaled in-reg by csl=eb[it]), 16-way K-split,
//           LDS reduce, Z-divide + squash -> vT[it] WT (+out on it==2).
//   g(it):  G = xT.vT[it] MFMA -> w-contract -> bij (LDS-resident) ->
//           cs=exp -> Z[it+1] agent-atomicAdd + eb[it] WT.
// Softmax deferred: fragments carry unnormalized exp, sq divides by Z_l.
// wpT pad rows (o==7) are exact zeros. Iter-3 bij update dead -> skipped.
// 256 blocks x 1024 thr = 1 block/CU, all resident -> spin barrier safe.

#define NB 512
#define NI 1152
#define NLO 112
#define NIK 9216
#define NPAD 128             // padded N: n = l*8+o, o==7 is zero pad

typedef __attribute__((ext_vector_type(8))) short bf16x8;
typedef __attribute__((ext_vector_type(4))) float f32x4;

__device__ __forceinline__ ushort f2bf(float f) {
    __hip_bfloat16 h = __float2bfloat16(f);
    return *(ushort*)&h;
}
__device__ __forceinline__ float bf2f(short s) {
    union { unsigned int u; float f; } v;
    v.u = ((unsigned int)(unsigned short)s) << 16;
    return v.f;
}

// agent-scope (L2-bypass, L3-coherent) helpers -- staging paths only
__device__ __forceinline__ void st_wt32(uint* p, uint v) {
    __hip_atomic_store(p, v, __ATOMIC_RELAXED, __HIP_MEMORY_SCOPE_AGENT);
}

// fenced barrier (post-prep only): publish normal stores via L2 wbinv
__device__ __forceinline__ void gbar_fence(int* ctr, int target) {
    __syncthreads();
    if (threadIdx.x == 0) {
        __threadfence();
        __hip_atomic_fetch_add(ctr, 1, __ATOMIC_RELAXED, __HIP_MEMORY_SCOPE_AGENT);
        while (__hip_atomic_load(ctr, __ATOMIC_RELAXED, __HIP_MEMORY_SCOPE_AGENT) < target)
            __builtin_amdgcn_s_sleep(2);
        __threadfence();
    }
    __syncthreads();
    __builtin_amdgcn_sched_barrier(0);
}

// fenceless barrier: producers' WT stores already at L3; consumers read
// virgin addresses only. Just drain + flag + spin.
__device__ __forceinline__ void gbar_fast(int* ctr, int target) {
    __syncthreads();
    if (threadIdx.x == 0) {
        asm volatile("s_waitcnt vmcnt(0)" ::: "memory");
        __hip_atomic_fetch_add(ctr, 1, __ATOMIC_RELAXED, __HIP_MEMORY_SCOPE_AGENT);
        while (__hip_atomic_load(ctr, __ATOMIC_RELAXED, __HIP_MEMORY_SCOPE_AGENT) < target)
            __builtin_amdgcn_s_sleep(2);
    }
    __syncthreads();
    __builtin_amdgcn_sched_barrier(0);
}

__global__ __launch_bounds__(1024) void route_all(
        const float* __restrict__ x, const float* __restrict__ w,
        float* __restrict__ out,
        ushort* __restrict__ xbf, ushort* __restrict__ xT,
        ushort* __restrict__ wpT,
        float* __restrict__ eb0, float* __restrict__ eb1,
        ushort* __restrict__ vT0, ushort* __restrict__ vT1,
        float* __restrict__ Zbuf, int* __restrict__ bar) {
    __shared__ ushort tileA[64][68];   // 8.7 KB  (prep conv_x)
    __shared__ ushort tileW[NPAD][66]; // 16.9 KB (prep wpT build)
    __shared__ float csl[NI * 2];      // 9.2 KB  (eb staged, [i][lsel])
    __shared__ float sp[16][16][16];   // 16 KB   (sq K-split reduce)
    __shared__ float ss[16][16];
    __shared__ float facs[16][2];
    __shared__ float zi[2];
    __shared__ float bs[4][8][16];
    __shared__ float cs[128];
    __shared__ float bij_s[128];       // bij, persists across iterations
    const int bid = blockIdx.x;
    const int t = threadIdx.x;
    const int wv = t >> 6, lane = t & 63;
    const int row = lane & 15, quad = lane >> 4;

    // ---------------- prep (jobs strided over 256 blocks) ----------------
    for (int job = bid; job < 1296; job += 256) {
        if (job < 1152) {              // conv_x: x fp32 -> xbf + xT (bf16)
            int kg = job % 144, bg = job / 144;
            int k0 = kg * 64, b0 = bg * 64;
            if (t < 1024) {
                int r = t >> 4, c4 = (t & 15) * 4;
                float4 f = *(const float4*)&x[(size_t)(b0 + r) * NIK + k0 + c4];
                ushort4 u = { f2bf(f.x), f2bf(f.y), f2bf(f.z), f2bf(f.w) };
                *(ushort4*)&xbf[(size_t)(b0 + r) * NIK + k0 + c4] = u;
                tileA[r][c4] = u.x; tileA[r][c4 + 1] = u.y;
                tileA[r][c4 + 2] = u.z; tileA[r][c4 + 3] = u.w;
            }
            __syncthreads();
            if (t < 1024) {
                int kr = t >> 4, c4 = (t & 15) * 4;
                ushort4 u = { tileA[c4][kr], tileA[c4 + 1][kr],
                              tileA[c4 + 2][kr], tileA[c4 + 3][kr] };
                *(ushort4*)&xT[(size_t)(k0 + kr) * NB + b0 + c4] = u;
            }
            __syncthreads();
        } else {                       // wpT: w fp32 -> padded bf16 [np][ik]
            int wb = job - 1152;       // 0..143
            int ik0 = wb * 64;
            for (int e = t; e < 8192; e += 1024) {
                int ikl = e >> 7, np = e & 127;
                int l = np >> 3, o = np & 7;
                float wf = (o < 7) ? w[(size_t)(ik0 + ikl) * NLO + l * 7 + o] : 0.f;
                tileW[np][ikl] = f2bf(wf);
            }
            __syncthreads();
            for (int e = t; e < 8192; e += 1024) {
                int np = e >> 6, ikl = e & 63;
                wpT[(size_t)np * NIK + ik0 + ikl] = tileW[np][ikl];
            }
            __syncthreads();
        }
    }
    int barv = 256;
    gbar_fence(bar, barv);             // publish xbf/xT/wpT; flush fill poison

    // ---------------- routing loop ----------------
    const int mt = bid & 31, ng = bid >> 5;
    const int b0 = mt * 16, n0 = ng * 16;
    const int k0 = wv * 576;           // 16-way K-split of 9216
    const int lsel = row >> 3;
    const int i0 = (k0 >> 3) + quad;   // i of this lane's fragment at ks=0
    const ushort* ap = xbf + (size_t)(b0 + row) * NIK + k0 + quad * 8;
    const ushort* bp = wpT + (size_t)(n0 + row) * NIK + k0 + quad * 8;

    for (int it = 0; it < 3; ++it) {
        // ---- stage eb columns (virgin addrs, L3-fresh) + zi ----
        if (it == 0) {
            for (int e = t; e < NI * 2; e += 1024) csl[e] = 1.0f;
            if (t < 2) zi[t] = 1.0f / 1152.0f;
        } else {
            const float* ebr = (it == 1) ? eb0 : eb1;
            for (int e = t; e < NI * 2; e += 1024)
                csl[e] = ebr[(size_t)(e >> 1) * 16 + ng * 2 + (e & 1)];
            if (t < 2) zi[t] = 1.0f / Zbuf[it * 64 + ng * 2 + t];
        }
        __syncthreads();
        // ---- sq GEMM: B = wpT scaled in-register by csl ----
        f32x4 acc = {0.f, 0.f, 0.f, 0.f};
        #pragma unroll 6
        for (int ks = 0; ks < 18; ++ks) {      // 576/32
            bf16x8 a = *(const bf16x8*)(ap + ks * 32);
            bf16x8 wf = *(const bf16x8*)(bp + ks * 32);
            float cv = csl[(i0 + ks * 4) * 2 + lsel];
            bf16x8 b;
            #pragma unroll
            for (int j = 0; j < 8; ++j) b[j] = (short)f2bf(bf2f(wf[j]) * cv);
            acc = __builtin_amdgcn_mfma_f32_16x16x32_bf16(a, b, acc, 0, 0, 0);
        }
        #pragma unroll
        for (int r = 0; r < 4; ++r) sp[wv][quad * 4 + r][row] = acc[r];
        __syncthreads();
        if (t < 256) {
            int m = t >> 4, n = t & 15;
            float sv = 0.f;
            #pragma unroll
            for (int w8 = 0; w8 < 16; ++w8) sv += sp[w8][m][n];
            ss[m][n] = sv * zi[n >> 3];
        }
        __syncthreads();
        if (t < 32) {
            int m = t >> 1, ll = t & 1;
            float sq = 0.f;
            #pragma unroll
            for (int o = 0; o < 8; ++o) { float e = ss[m][ll * 8 + o]; sq += e * e; }
            facs[m][ll] = sqrtf(sq) / (1.0f + sq);   // == (sq/(1+sq))/norm
        }
        __syncthreads();
        if (t < 256) {                 // v values -> sp[0] (sq reduce done)
            int m = t >> 4, n = t & 15;
            float vv = ss[m][n] * facs[m][n >> 3];
            sp[0][m][n] = vv;
            if (it == 2) {
                int o = n & 7, lg = ng * 2 + (n >> 3);
                if (o < 7) out[(size_t)(b0 + m) * NLO + o * 16 + lg] = vv;
            }
        }
        if (it == 2) break;            // final v written; kernel-end flush
        __syncthreads();
        if (t < 128) {                 // WT-pack vT[it]: 2 m's per uint
            int n = t >> 3, mp = t & 7;
            int o = n & 7, lg = ng * 2 + (n >> 3);
            if (o < 7) {
                uint lo = f2bf(sp[0][2 * mp][n]);
                uint hi = f2bf(sp[0][2 * mp + 1][n]);
                ushort* vTw = (it == 0) ? vT0 : vT1;
                st_wt32((uint*)(vTw + (size_t)(o * 16 + lg) * NB + b0 + 2 * mp),
                        lo | (hi << 16));
            }
        }
        barv += 256;
        gbar_fast(bar, barv);          // vT[it] at L3

        // ---- g phase (blocks 0..143; others fall through to barrier) ----
        if (bid < 144) {
            const ushort* vTr = (it == 0) ? vT0 : vT1;
            int qt = wv & 3;                 // B-quarter (128 batch each)
            int mtg = wv >> 2;               // 0..3 ik-tile
            int m0 = bid * 64 + mtg * 16;
            int kb0 = qt * 128;
            const ushort* gap = xT + (size_t)(m0 + row) * NB + kb0 + quad * 8;
            const ushort* gbp = vTr + (size_t)row * NB + kb0 + quad * 8;
            f32x4 gacc[7];
            #pragma unroll
            for (int nt = 0; nt < 7; ++nt) gacc[nt] = (f32x4){0.f, 0.f, 0.f, 0.f};
            for (int ks = 0; ks < 4; ++ks) {                 // 128/32
                bf16x8 a = *(const bf16x8*)(gap + ks * 32);
                #pragma unroll
                for (int nt = 0; nt < 7; ++nt) {
                    bf16x8 bfr = *(const bf16x8*)(gbp + (size_t)nt * 16 * NB + ks * 32);
                    gacc[nt] = __builtin_amdgcn_mfma_f32_16x16x32_bf16(a, bfr, gacc[nt], 0, 0, 0);
                }
            }
            // lane holds G[ik = m0+quad*4+r][o*16+l], o = nt, l = row
            float S = 0.f;
            #pragma unroll
            for (int r = 0; r < 4; ++r) {
                int ik = m0 + quad * 4 + r;
                const float* wr = w + (size_t)ik * NLO + row * 7;
                float p = 0.f;
                #pragma unroll
                for (int o = 0; o < 7; ++o) p += wr[o] * gacc[o][r];
                S += p;
            }
            float Sp = __shfl_down(S, 16);                   // partner quad's sum
            if ((quad & 1) == 0)
                bs[qt][mtg * 2 + (quad >> 1)][row] = (S + Sp) * (1.0f / 512.0f);
            __syncthreads();
            if (t < 128) {
                float val = bs[0][t >> 4][t & 15] + bs[1][t >> 4][t & 15]
                          + bs[2][t >> 4][t & 15] + bs[3][t >> 4][t & 15];
                if (it) val += bij_s[t];
                bij_s[t] = val;        // bij stays in LDS across iterations
                float e = expf(val);
                cs[t] = e;             // cs[il*16 + l]
                int i = bid * 8 + (t >> 4);
                float* ebw = (it == 0) ? eb0 : eb1;
                st_wt32((uint*)&ebw[(size_t)i * 16 + (t & 15)], __float_as_uint(e));
            }
            __syncthreads();
            if (t < 16) {
                float z = 0.f;
                #pragma unroll
                for (int j = 0; j < 8; ++j) z += cs[j * 16 + t];
                __hip_atomic_fetch_add(&Zbuf[(it + 1) * 64 + t], z,
                                       __ATOMIC_RELAXED, __HIP_MEMORY_SCOPE_AGENT);
            }
        }
        barv += 256;
        gbar_fast(bar, barv);          // eb[it]/Z[it+1] at L3
    }
}

extern "C" void kernel_launch(void* const* d_in, const int* in_sizes, int n_in,
                              void* d_out, int out_size, void* d_ws, size_t ws_size,
                              hipStream_t stream) {
    const float* x = (const float*)d_in[0];   // [512][9216]
    const float* w = (const float*)d_in[1];   // [9216][112]
    float* out = (float*)d_out;               // [512][112]
    float* ws = (float*)d_ws;
    float*  Zbuf = ws;                                    // 3*64 floats (768B)
    int*    bar  = (int*)((char*)d_ws + 768);             // own line
    float*  eb0  = (float*)((char*)d_ws + 1024);          // 1152*16 f32
    float*  eb1  = eb0 + (size_t)NI * 16;                 // 1152*16 f32
    ushort* xbf  = (ushort*)(eb1 + (size_t)NI * 16);      // 512*9216
    ushort* xT   = xbf + (size_t)NB * NIK;                // 9216*512
    ushort* wpT  = xT + (size_t)NIK * NB;                 // 128*9216 static
    ushort* vT0  = wpT + (size_t)NPAD * NIK;              // 112*512
    ushort* vT1  = vT0 + (size_t)NLO * NB;                // 112*512
    hipMemsetAsync(ws, 0, 1024, stream);                  // Zbuf + bar
    route_all<<<256, 1024, 0, stream>>>(x, w, out, xbf, xT, wpT, eb0, eb1,
                                        vT0, vT1, Zbuf, bar);
}

// Round 9
// 176.393 us; speedup vs baseline: 1.1760x; 1.1760x over previous
//
#include <hip/hip_runtime.h>
#include <hip/hip_bf16.h>

// B=512, I=1152, K=8, L=16, O=7; IK=9216, LO=112.
// Round-8: R3's 6-dispatch structure (best measured: 172.65us) with ONE
// change: prep0's conv_x jobs are remapped for XCD locality.
//   sq's mapping mt=bid&31 gives XCD x (=bid%8) an EXCLUSIVE mt set
//   {x,x+8,x+16,x+24}. Old prep wrote 64-row chunks spanning 4 XCDs ->
//   sq's xbf slice was written by OTHER XCDs' L2s (cold L3/HBM miss,
//   ~35us latency-serialized in sq0 per the R7 analysis). New prep uses
//   16-row jobs with mtj=bid%32 -> writer XCD == mtj%8 == reader XCD
//   automatically -> sq A-operand reads are same-L2 dirty hits IF L2
//   content survives kernel boundaries (this round's measured question).
//   Correctness-safe under ANY dispatch mapping: cross-kernel visibility
//   is the driver's responsibility (proven by R0-R3 passing); a wrong
//   mapping assumption only costs speed.
// Everything else byte-identical to R3:
//   prep0: x->xbf,xT (bf16) + wpT/wps = bf16(w) padded (STATIC) + Z init
//   sq_gemm: s = xbf . wps (pre-scaled B), 8-wave K-split, 6-deep ring
//            prefetch, LDS reduce, Z-divide + squash -> vT (+out last)
//   g_wc: G = xT.vT MFMA -> w-contract -> bij -> cs=exp -> Z + wps rescale
// Softmax deferred: wps carries unnormalized exp, sq divides by Z_l.
// wps pad rows (o==7) are exact zeros. Iter-3 bij update dead -> skipped.

#define NB 512
#define NI 1152
#define NLO 112
#define NIK 9216
#define NPAD 128             // padded N: n = l*8+o, o==7 is zero pad

typedef __attribute__((ext_vector_type(8))) short bf16x8;
typedef __attribute__((ext_vector_type(4))) float f32x4;

__device__ __forceinline__ ushort f2bf(float f) {
    __hip_bfloat16 h = __float2bfloat16(f);
    return *(ushort*)&h;
}
__device__ __forceinline__ float bf2f(short s) {
    union { unsigned int u; float f; } v;
    v.u = ((unsigned int)(unsigned short)s) << 16;
    return v.f;
}

// ---- conv_x16: 16-b-row x 64-k tile; writer XCD == sq-reader XCD ----
// bid in [0, 4608): mtj = bid%32 (16-row xbf slice), kg = bid/32 (k chunk).
// XCD(bid)=bid%8 == mtj%8 == XCD of the sq block with mt==mtj. xbf rows
// [16*mtj, +16) land dirty in that XCD's L2 across all 144 kg jobs.
__device__ __forceinline__ void conv_x16(const float* __restrict__ x,
                                         ushort* __restrict__ xbf,
                                         ushort* __restrict__ xT, int bid) {
    __shared__ ushort tile[16][68];
    int mtj = bid & 31, kg = bid >> 5;
    int b0 = mtj * 16, k0 = kg * 64;
    int t = threadIdx.x;               // 256 threads, one float4 each
    {
        int r = t >> 4, c4 = (t & 15) * 4;
        float4 f = *(const float4*)&x[(size_t)(b0 + r) * NIK + k0 + c4];
        ushort4 u = { f2bf(f.x), f2bf(f.y), f2bf(f.z), f2bf(f.w) };
        *(ushort4*)&xbf[(size_t)(b0 + r) * NIK + k0 + c4] = u;
        tile[r][c4] = u.x; tile[r][c4 + 1] = u.y; tile[r][c4 + 2] = u.z; tile[r][c4 + 3] = u.w;
    }
    __syncthreads();
    for (int e = t; e < 512; e += 256) {
        int kr = e >> 3, c2 = (e & 7) * 2;
        ushort2 u = { tile[c2][kr], tile[c2 + 1][kr] };
        *(ushort2*)&xT[(size_t)(k0 + kr) * NB + b0 + c2] = u;
    }
}

// ---- prep0: conv_x16 (0..4607) + static wpT/wps build (4608..4751) ----
__global__ __launch_bounds__(256) void prep0(const float* __restrict__ x,
                                             ushort* __restrict__ xbf,
                                             ushort* __restrict__ xT,
                                             const float* __restrict__ w,
                                             ushort* __restrict__ wpT,
                                             ushort* __restrict__ wps,
                                             float* __restrict__ Z) {
    if (blockIdx.x < 4608) { conv_x16(x, xbf, xT, blockIdx.x); return; }
    __shared__ ushort tile[NPAD][66];
    int t = threadIdx.x;
    int wb = blockIdx.x - 4608;      // 0..143
    int ik0 = wb * 64;
    if (blockIdx.x == 4608 && t < 48) Z[t] = (t < 16) ? 1152.0f : 0.0f;
    for (int e = t; e < 8192; e += 256) {
        int ikl = e >> 7, np = e & 127;
        int l = np >> 3, o = np & 7;
        float wv = (o < 7) ? w[(size_t)(ik0 + ikl) * NLO + l * 7 + o] : 0.f;
        tile[np][ikl] = f2bf(wv);
    }
    __syncthreads();
    for (int e = t; e < 8192; e += 256) {
        int np = e >> 6, ikl = e & 63;
        ushort v = tile[np][ikl];
        wpT[(size_t)np * NIK + ik0 + ikl] = v;   // static master copy
        wps[(size_t)np * NIK + ik0 + ikl] = v;   // iter-0 scaled copy (eb=1)
    }
}

// ---- sq_gemm: fused s-GEMM + Z-divide + squash -> vT/out ----
// 256 blocks x 512 thr (8 waves, K-split 9216/8=1152 -> 36 K-steps/wave).
// __launch_bounds__(512,2): VGPR ceiling 256 so the 6-deep ring prefetch
// stays in registers (12 outstanding 16B loads/wave).
// XCD x (=bid%8) reads xbf rows for mt in {x,x+8,x+16,x+24} -- written by
// same-XCD prep blocks (conv_x16 mapping) -> local-L2 hits if retained.
__global__ __launch_bounds__(512, 2) void sq_gemm(const ushort* __restrict__ xbf,
                                                  const ushort* __restrict__ wps,
                                                  const float* __restrict__ Zit,
                                                  ushort* __restrict__ vT,
                                                  float* __restrict__ out, int wout) {
    __shared__ float sp[8][16][16];    // [wave][m][n] 8 KB
    __shared__ float ss[16][16];
    __shared__ float facs[16][2];
    __shared__ float zi[2];
    int bid = blockIdx.x;
    int mt = bid & 31, ng = bid >> 5;
    int b0 = mt * 16, n0 = ng * 16;
    int t = threadIdx.x;
    int wv = t >> 6, lane = t & 63;
    int row = lane & 15, quad = lane >> 4;
    int k0 = wv * 1152;                // 8-way K-split of 9216
    if (t < 2) zi[t] = 1.0f / Zit[ng * 2 + t];
    const ushort* ap = xbf + (size_t)(b0 + row) * NIK + k0 + quad * 8;
    const ushort* bp = wps + (size_t)(n0 + row) * NIK + k0 + quad * 8;
    // 6-deep ring prefetch; fully unrolled -> all ring indices static
    bf16x8 ab[6], bb[6];
    #pragma unroll
    for (int p = 0; p < 6; ++p) {
        ab[p] = *(const bf16x8*)(ap + p * 32);
        bb[p] = *(const bf16x8*)(bp + p * 32);
    }
    f32x4 acc = {0.f, 0.f, 0.f, 0.f};
    #pragma unroll
    for (int ks = 0; ks < 36; ++ks) {  // 1152/32
        int s = ks % 6;
        acc = __builtin_amdgcn_mfma_f32_16x16x32_bf16(ab[s], bb[s], acc, 0, 0, 0);
        if (ks < 30) {
            ab[s] = *(const bf16x8*)(ap + (ks + 6) * 32);
            bb[s] = *(const bf16x8*)(bp + (ks + 6) * 32);
        }
    }
    #pragma unroll
    for (int r = 0; r < 4; ++r) sp[wv][quad * 4 + r][row] = acc[r];
    __syncthreads();
    if (t < 256) {
        int m = t >> 4, n = t & 15;
        float sv = 0.f;
        #pragma unroll
        for (int w8 = 0; w8 < 8; ++w8) sv += sp[w8][m][n];
        ss[m][n] = sv * zi[n >> 3];
    }
    __syncthreads();
    if (t < 32) {
        int m = t >> 1, ll = t & 1;
        float sq = 0.f;
        #pragma unroll
        for (int o = 0; o < 8; ++o) { float e = ss[m][ll * 8 + o]; sq += e * e; }
        facs[m][ll] = sqrtf(sq) / (1.0f + sq);   // == (sq/(1+sq))/norm; pad adds 0
    }
    __syncthreads();
    if (t < 256) {
        int m = t >> 4, n = t & 15;
        int o = n & 7, lg = ng * 2 + (n >> 3);
        if (o < 7) {
            float vv = ss[m][n] * facs[m][n >> 3];
            vT[(size_t)(o * 16 + lg) * NB + b0 + m] = f2bf(vv);
            if (wout) out[(size_t)(b0 + m) * NLO + o * 16 + lg] = vv;
        }
    }
}

// ---- g_wc: G-MFMA + w-contraction + block-local bij update + eb=exp + Z
//      + wps rescale for the next iteration. 144 blocks x 512 threads. ----
__global__ __launch_bounds__(512) void g_wc(const ushort* __restrict__ xT,
                                            const ushort* __restrict__ vT,
                                            const float* __restrict__ w,
                                            float* __restrict__ bij,
                                            const ushort* __restrict__ wpT,
                                            ushort* __restrict__ wps,
                                            float* __restrict__ Zit, int accum) {
    __shared__ float bs[2][8][16];
    __shared__ float cs[128];
    int t = threadIdx.x;
    int wv = t >> 6;                 // 0..7
    int lane = t & 63;
    int half = wv & 1;
    int mt = wv >> 1;                // 0..3
    int m0 = blockIdx.x * 64 + mt * 16;
    int kb0 = half * 256;
    int row = lane & 15, quad = lane >> 4;
    const ushort* ap = xT + (size_t)(m0 + row) * NB + kb0 + quad * 8;
    const ushort* bp = vT + (size_t)row * NB + kb0 + quad * 8;    // + nt*16*NB
    f32x4 acc[7];
    #pragma unroll
    for (int nt = 0; nt < 7; ++nt) acc[nt] = (f32x4){0.f, 0.f, 0.f, 0.f};
    // load-use interleave: one A-frag + one B-frag live at a time
    for (int ks = 0; ks < 8; ++ks) {                 // 256/32
        bf16x8 a = *(const bf16x8*)(ap + ks * 32);
        #pragma unroll
        for (int nt = 0; nt < 7; ++nt) {
            bf16x8 bfr = *(const bf16x8*)(bp + (size_t)nt * 16 * NB + ks * 32);
            acc[nt] = __builtin_amdgcn_mfma_f32_16x16x32_bf16(a, bfr, acc[nt], 0, 0, 0);
        }
    }
    // lane holds G[ik = m0+quad*4+r][o*16+l], o = nt, l = row
    float S = 0.f;
    #pragma unroll
    for (int r = 0; r < 4; ++r) {
        int ik = m0 + quad * 4 + r;
        const float* wr = w + (size_t)ik * NLO + row * 7;
        float p = 0.f;
        #pragma unroll
        for (int o = 0; o < 7; ++o) p += wr[o] * acc[o][r];
        S += p;
    }
    float Sp = __shfl_down(S, 16);                   // partner quad's 4-ik sum
    if ((quad & 1) == 0)
        bs[half][mt * 2 + (quad >> 1)][row] = (S + Sp) * (1.0f / 512.0f);
    __syncthreads();
    if (t < 128) {
        int il = t >> 4, l = t & 15;
        int i = blockIdx.x * 8 + il;
        float val = bs[0][il][l] + bs[1][il][l];
        if (accum) val += bij[i * 16 + l];
        bij[i * 16 + l] = val;
        cs[t] = expf(val);           // cs[il*16 + l]
    }
    __syncthreads();
    if (t < 16) {
        float z = 0.f;
        #pragma unroll
        for (int j = 0; j < 8; ++j) z += cs[j * 16 + t];
        atomicAdd(&Zit[t], z);
    }
    // rescale this block's 64 ik-columns: wps = bf16(cs * wpT) for next iter.
    int ik0 = blockIdx.x * 64;
    for (int e = t; e < 2048; e += 512) {
        int np = e >> 4, i4 = (e & 15) * 4;
        float sc = cs[(i4 >> 3) * 16 + (np >> 3)];
        ushort4 wv4 = *(const ushort4*)&wpT[(size_t)np * NIK + ik0 + i4];
        ushort4 o4 = { f2bf(bf2f((short)wv4.x) * sc), f2bf(bf2f((short)wv4.y) * sc),
                       f2bf(bf2f((short)wv4.z) * sc), f2bf(bf2f((short)wv4.w) * sc) };
        *(ushort4*)&wps[(size_t)np * NIK + ik0 + i4] = o4;
    }
}

extern "C" void kernel_launch(void* const* d_in, const int* in_sizes, int n_in,
                              void* d_out, int out_size, void* d_ws, size_t ws_size,
                              hipStream_t stream) {
    const float* x = (const float*)d_in[0];   // [512][9216]
    const float* w = (const float*)d_in[1];   // [9216][112]
    float* out = (float*)d_out;               // [512][112]
    float* ws = (float*)d_ws;
    float*  f_bij  = ws;                                  // 18432
    float*  f_Z    = f_bij + NI * 16;                     // 3*16
    ushort* xbf    = (ushort*)(f_Z + 48);                 // 512*9216
    ushort* xT     = xbf + (size_t)NB * NIK;              // 9216*512
    ushort* wpT    = xT + (size_t)NIK * NB;               // 128*9216 static
    ushort* wps    = wpT + (size_t)NPAD * NIK;            // 128*9216 scaled
    ushort* vT     = wps + (size_t)NPAD * NIK;            // 112*512
    prep0<<<4752, 256, 0, stream>>>(x, xbf, xT, w, wpT, wps, f_Z);
    for (int it = 0; it < 3; ++it) {
        sq_gemm<<<256, 512, 0, stream>>>(xbf, wps, f_Z + it * 16, vT, out,
                                         it == 2 ? 1 : 0);
        if (it < 2)
            g_wc<<<144, 512, 0, stream>>>(xT, vT, w, f_bij, wpT, wps,
                                          f_Z + (it + 1) * 16, it);
    }
}

// Round 10
// 173.014 us; speedup vs baseline: 1.1990x; 1.0195x over previous
//
#include <hip/hip_runtime.h>
#include <hip/hip_bf16.h>

// B=512, I=1152, K=8, L=16, O=7; IK=9216, LO=112.
// Round-9: R3's 6-dispatch structure (best measured: 172.65us; prep and sq
// byte-identical to R3) with ONE change: g_wc re-gridded 144x512 -> 288x256.
//   R3's g used 144 blocks (1 block/CU max) -> 112 of 256 CUs IDLE during
//   both g dispatches. Same 1152 total waves now spread across all CUs:
//   each block owns 4 i's (32 ik rows), 4 waves = 2 ik-tiles x 2 B-halves.
//   Exclusive bij/wps ownership preserved (bij rows 4*bid..+3).
// R8 lesson folded in: L2 does NOT survive kernel boundaries (implicit
// acquire/invalidate at launch -- how cross-XCD visibility is guaranteed),
// so inter-kernel L2-locality engineering is structurally impossible; all
// kernels read from L3. Latency-spread (more active CUs) is the only lever.
//   prep0: x->xbf,xT (bf16) + wpT/wps = bf16(w) padded (STATIC) + Z init
//   sq_gemm: s = xbf . wps (pre-scaled B), 8-wave K-split, 6-deep ring
//            prefetch, LDS reduce, Z-divide + squash -> vT (+out last)
//   g_wc: G = xT.vT MFMA -> w-contract -> bij -> cs=exp -> Z + wps rescale
// Softmax deferred: wps carries unnormalized exp, sq divides by Z_l.
// wps pad rows (o==7) are exact zeros. Iter-3 bij update dead -> skipped.

#define NB 512
#define NI 1152
#define NLO 112
#define NIK 9216
#define NPAD 128             // padded N: n = l*8+o, o==7 is zero pad

typedef __attribute__((ext_vector_type(8))) short bf16x8;
typedef __attribute__((ext_vector_type(4))) float f32x4;

__device__ __forceinline__ ushort f2bf(float f) {
    __hip_bfloat16 h = __float2bfloat16(f);
    return *(ushort*)&h;
}
__device__ __forceinline__ float bf2f(short s) {
    union { unsigned int u; float f; } v;
    v.u = ((unsigned int)(unsigned short)s) << 16;
    return v.f;
}

// ---- conv_x body: x fp32 -> xbf [b][ik] and xT [ik][b], both bf16 ----
__device__ __forceinline__ void conv_x_body(const float* __restrict__ x,
                                            ushort* __restrict__ xbf,
                                            ushort* __restrict__ xT, int bid) {
    __shared__ ushort tile[64][68];
    int kg = bid % 144, bg = bid / 144;
    int k0 = kg * 64, b0 = bg * 64;
    int t = threadIdx.x;
    for (int e = t; e < 1024; e += 256) {
        int r = e >> 4, c4 = (e & 15) * 4;
        float4 f = *(const float4*)&x[(size_t)(b0 + r) * NIK + k0 + c4];
        ushort4 u = { f2bf(f.x), f2bf(f.y), f2bf(f.z), f2bf(f.w) };
        *(ushort4*)&xbf[(size_t)(b0 + r) * NIK + k0 + c4] = u;
        tile[r][c4] = u.x; tile[r][c4 + 1] = u.y; tile[r][c4 + 2] = u.z; tile[r][c4 + 3] = u.w;
    }
    __syncthreads();
    for (int e = t; e < 1024; e += 256) {
        int kr = e >> 4, c4 = (e & 15) * 4;
        ushort4 u = { tile[c4][kr], tile[c4 + 1][kr], tile[c4 + 2][kr], tile[c4 + 3][kr] };
        *(ushort4*)&xT[(size_t)(k0 + kr) * NB + b0 + c4] = u;
    }
}

// ---- prep0: conv_x (0..1151) + static wpT/wps build + Z init (1152..1295) ----
__global__ __launch_bounds__(256) void prep0(const float* __restrict__ x,
                                             ushort* __restrict__ xbf,
                                             ushort* __restrict__ xT,
                                             const float* __restrict__ w,
                                             ushort* __restrict__ wpT,
                                             ushort* __restrict__ wps,
                                             float* __restrict__ Z) {
    if (blockIdx.x < 1152) { conv_x_body(x, xbf, xT, blockIdx.x); return; }
    __shared__ ushort tile[NPAD][66];
    int t = threadIdx.x;
    int wb = blockIdx.x - 1152;      // 0..143
    int ik0 = wb * 64;
    if (blockIdx.x == 1152 && t < 48) Z[t] = (t < 16) ? 1152.0f : 0.0f;
    for (int e = t; e < 8192; e += 256) {
        int ikl = e >> 7, np = e & 127;
        int l = np >> 3, o = np & 7;
        float wv = (o < 7) ? w[(size_t)(ik0 + ikl) * NLO + l * 7 + o] : 0.f;
        tile[np][ikl] = f2bf(wv);
    }
    __syncthreads();
    for (int e = t; e < 8192; e += 256) {
        int np = e >> 6, ikl = e & 63;
        ushort v = tile[np][ikl];
        wpT[(size_t)np * NIK + ik0 + ikl] = v;   // static master copy
        wps[(size_t)np * NIK + ik0 + ikl] = v;   // iter-0 scaled copy (eb=1)
    }
}

// ---- sq_gemm: fused s-GEMM + Z-divide + squash -> vT/out (R3-exact) ----
// 256 blocks x 512 thr (8 waves, K-split 9216/8=1152 -> 36 K-steps/wave).
__global__ __launch_bounds__(512, 2) void sq_gemm(const ushort* __restrict__ xbf,
                                                  const ushort* __restrict__ wps,
                                                  const float* __restrict__ Zit,
                                                  ushort* __restrict__ vT,
                                                  float* __restrict__ out, int wout) {
    __shared__ float sp[8][16][16];    // [wave][m][n] 8 KB
    __shared__ float ss[16][16];
    __shared__ float facs[16][2];
    __shared__ float zi[2];
    int bid = blockIdx.x;
    int mt = bid & 31, ng = bid >> 5;
    int b0 = mt * 16, n0 = ng * 16;
    int t = threadIdx.x;
    int wv = t >> 6, lane = t & 63;
    int row = lane & 15, quad = lane >> 4;
    int k0 = wv * 1152;                // 8-way K-split of 9216
    if (t < 2) zi[t] = 1.0f / Zit[ng * 2 + t];
    const ushort* ap = xbf + (size_t)(b0 + row) * NIK + k0 + quad * 8;
    const ushort* bp = wps + (size_t)(n0 + row) * NIK + k0 + quad * 8;
    // 6-deep ring prefetch; fully unrolled -> all ring indices static
    bf16x8 ab[6], bb[6];
    #pragma unroll
    for (int p = 0; p < 6; ++p) {
        ab[p] = *(const bf16x8*)(ap + p * 32);
        bb[p] = *(const bf16x8*)(bp + p * 32);
    }
    f32x4 acc = {0.f, 0.f, 0.f, 0.f};
    #pragma unroll
    for (int ks = 0; ks < 36; ++ks) {  // 1152/32
        int s = ks % 6;
        acc = __builtin_amdgcn_mfma_f32_16x16x32_bf16(ab[s], bb[s], acc, 0, 0, 0);
        if (ks < 30) {
            ab[s] = *(const bf16x8*)(ap + (ks + 6) * 32);
            bb[s] = *(const bf16x8*)(bp + (ks + 6) * 32);
        }
    }
    #pragma unroll
    for (int r = 0; r < 4; ++r) sp[wv][quad * 4 + r][row] = acc[r];
    __syncthreads();
    if (t < 256) {
        int m = t >> 4, n = t & 15;
        float sv = 0.f;
        #pragma unroll
        for (int w8 = 0; w8 < 8; ++w8) sv += sp[w8][m][n];
        ss[m][n] = sv * zi[n >> 3];
    }
    __syncthreads();
    if (t < 32) {
        int m = t >> 1, ll = t & 1;
        float sq = 0.f;
        #pragma unroll
        for (int o = 0; o < 8; ++o) { float e = ss[m][ll * 8 + o]; sq += e * e; }
        facs[m][ll] = sqrtf(sq) / (1.0f + sq);   // == (sq/(1+sq))/norm; pad adds 0
    }
    __syncthreads();
    if (t < 256) {
        int m = t >> 4, n = t & 15;
        int o = n & 7, lg = ng * 2 + (n >> 3);
        if (o < 7) {
            float vv = ss[m][n] * facs[m][n >> 3];
            vT[(size_t)(o * 16 + lg) * NB + b0 + m] = f2bf(vv);
            if (wout) out[(size_t)(b0 + m) * NLO + o * 16 + lg] = vv;
        }
    }
}

// ---- g_wc: G-MFMA + w-contraction + bij update + eb=exp + Z + wps rescale ----
// 288 blocks x 256 thr (4 waves = 2 ik-tiles x 2 B-halves). Block owns
// i = 4*bid..+3 (ik = 32*bid..+31) exclusively -> plain bij/wps writes,
// atomics only on Z. All 256 CUs active (R3's 144x512 left 112 CUs idle).
__global__ __launch_bounds__(256) void g_wc(const ushort* __restrict__ xT,
                                            const ushort* __restrict__ vT,
                                            const float* __restrict__ w,
                                            float* __restrict__ bij,
                                            const ushort* __restrict__ wpT,
                                            ushort* __restrict__ wps,
                                            float* __restrict__ Zit, int accum) {
    __shared__ float bs[2][4][16];
    __shared__ float cs[64];
    int t = threadIdx.x;
    int wv = t >> 6;                 // 0..3
    int lane = t & 63;
    int half = wv & 1;               // B-half (256 batch each)
    int mtg = wv >> 1;               // 0..1 ik-tile
    int m0 = blockIdx.x * 32 + mtg * 16;
    int kb0 = half * 256;
    int row = lane & 15, quad = lane >> 4;
    const ushort* ap = xT + (size_t)(m0 + row) * NB + kb0 + quad * 8;
    const ushort* bp = vT + (size_t)row * NB + kb0 + quad * 8;    // + nt*16*NB
    f32x4 acc[7];
    #pragma unroll
    for (int nt = 0; nt < 7; ++nt) acc[nt] = (f32x4){0.f, 0.f, 0.f, 0.f};
    // load-use interleave: one A-frag + one B-frag live at a time
    for (int ks = 0; ks < 8; ++ks) {                 // 256/32
        bf16x8 a = *(const bf16x8*)(ap + ks * 32);
        #pragma unroll
        for (int nt = 0; nt < 7; ++nt) {
            bf16x8 bfr = *(const bf16x8*)(bp + (size_t)nt * 16 * NB + ks * 32);
            acc[nt] = __builtin_amdgcn_mfma_f32_16x16x32_bf16(a, bfr, acc[nt], 0, 0, 0);
        }
    }
    // lane holds G[ik = m0+quad*4+r][o*16+l], o = nt, l = row
    float S = 0.f;
    #pragma unroll
    for (int r = 0; r < 4; ++r) {
        int ik = m0 + quad * 4 + r;
        const float* wr = w + (size_t)ik * NLO + row * 7;
        float p = 0.f;
        #pragma unroll
        for (int o = 0; o < 7; ++o) p += wr[o] * acc[o][r];
        S += p;
    }
    float Sp = __shfl_down(S, 16);                   // partner quad's 4-ik sum
    if ((quad & 1) == 0)
        bs[half][mtg * 2 + (quad >> 1)][row] = (S + Sp) * (1.0f / 512.0f);
    __syncthreads();
    if (t < 64) {
        int il = t >> 4, l = t & 15;
        int i = blockIdx.x * 4 + il;
        float val = bs[0][il][l] + bs[1][il][l];
        if (accum) val += bij[i * 16 + l];
        bij[i * 16 + l] = val;
        cs[t] = expf(val);           // cs[il*16 + l]
    }
    __syncthreads();
    if (t < 16) {
        float z = 0.f;
        #pragma unroll
        for (int j = 0; j < 4; ++j) z += cs[j * 16 + t];
        atomicAdd(&Zit[t], z);
    }
    // rescale this block's 32 ik-columns: wps = bf16(cs * wpT) for next iter.
    int ik0 = blockIdx.x * 32;
    for (int e = t; e < 1024; e += 256) {
        int np = e >> 3, i4 = (e & 7) * 4;   // i4 in {0,4,..,28}
        float sc = cs[(i4 >> 3) * 16 + (np >> 3)];
        ushort4 wv4 = *(const ushort4*)&wpT[(size_t)np * NIK + ik0 + i4];
        ushort4 o4 = { f2bf(bf2f((short)wv4.x) * sc), f2bf(bf2f((short)wv4.y) * sc),
                       f2bf(bf2f((short)wv4.z) * sc), f2bf(bf2f((short)wv4.w) * sc) };
        *(ushort4*)&wps[(size_t)np * NIK + ik0 + i4] = o4;
    }
}

extern "C" void kernel_launch(void* const* d_in, const int* in_sizes, int n_in,
                              void* d_out, int out_size, void* d_ws, size_t ws_size,
                              hipStream_t stream) {
    const float* x = (const float*)d_in[0];   // [512][9216]
    const float* w = (const float*)d_in[1];   // [9216][112]
    float* out = (float*)d_out;               // [512][112]
    float* ws = (float*)d_ws;
    float*  f_bij  = ws;                                  // 18432
    float*  f_Z    = f_bij + NI * 16;                     // 3*16
    ushort* xbf    = (ushort*)(f_Z + 48);                 // 512*9216
    ushort* xT     = xbf + (size_t)NB * NIK;              // 9216*512
    ushort* wpT    = xT + (size_t)NIK * NB;               // 128*9216 static
    ushort* wps    = wpT + (size_t)NPAD * NIK;            // 128*9216 scaled
    ushort* vT     = wps + (size_t)NPAD * NIK;            // 112*512
    prep0<<<1296, 256, 0, stream>>>(x, xbf, xT, w, wpT, wps, f_Z);
    for (int it = 0; it < 3; ++it) {
        sq_gemm<<<256, 512, 0, stream>>>(xbf, wps, f_Z + it * 16, vT, out,
                                         it == 2 ? 1 : 0);
        if (it < 2)
            g_wc<<<288, 256, 0, stream>>>(xT, vT, w, f_bij, wpT, wps,
                                          f_Z + (it + 1) * 16, it);
    }
}